// Round 1
// baseline (11619.570 us; speedup 1.0000x reference)
//
#include <hip/hip_runtime.h>
#include <math.h>

// Problem constants
// B=16, S=100, V=30000, H=512, E=300, T=50, MAXLEN=50, D=3H+E=1836
#define NEGV (-1000000.0f)

// ---- workspace layout (float element offsets) ----
constexpr size_t WS_WT_OUT = 0;                       // [1024][30000]
constexpr size_t WS_WT_IH  = 30720000;                // [1836][1536]
constexpr size_t WS_WT_HH  = 33540096;                // [512][1536]
constexpr size_t WS_WT_AT  = 34326528;                // [512][512]
constexpr size_t WS_WT_CP  = 34588672;                // [512][512]
constexpr size_t WS_XG     = 34850816;                // x for GRU, k-major [1836][16]
constexpr size_t WS_X2     = 34880192;                // [1024][16]  (context | hidden)
constexpr size_t WS_PGI    = 34896576;                // [8][1536][16]
constexpr size_t WS_PGH    = 35093184;                // [8][1536][16]
constexpr size_t WS_PTH    = 35289792;                // [4][512][16]
constexpr size_t WS_PTH2   = 35322560;                // [4][512][16]
constexpr size_t WS_HID    = 35355328;                // [16][512]
constexpr size_t WS_PREH   = 35363520;                // [16][512]
constexpr size_t WS_CSS    = 35371712;                // [16][100]
constexpr size_t WS_CVAL   = 35373312;                // [16][100]
constexpr size_t WS_COPYZ  = 35374912;                // [16]
constexpr size_t WS_MCUR   = 35374928;                // [16]
constexpr size_t WS_ZPART  = 35374944;                // [471][16]
constexpr size_t WS_ZTOT   = 35382480;                // [49][16]
constexpr size_t WS_INTS   = 35383264;                // int region starts here (element idx)
// int region sub-offsets (in ints, relative to ws base as int*)
constexpr size_t IP_CTOK = 0;     // [16][100]
constexpr size_t IP_EOS  = 1600;  // [16]
constexpr size_t IP_PS   = 1616;  // [16]
constexpr size_t IP_SEG  = 1632;  // [16]
constexpr size_t IP_IDX  = 1648;  // [16]
constexpr size_t IP_CLEN = 1664;  // [16]
// total ws need: ~35,384,944 floats = ~141.6 MB

constexpr size_t OUT_BSTRIDE = 1505000; // 50*30100
constexpr size_t IDX_OFF = 24080000;    // 16*50*30100

// ---------------- transpose: dst[C][R] = src[R][C] ----------------
__global__ void ktrans(const float* __restrict__ src, float* __restrict__ dst, int R, int C) {
  __shared__ float tile[32][33];
  const int t = threadIdx.x;
  const int lx = t & 31, ly = t >> 5; // 32 x 8
  const int r0 = blockIdx.x * 32, c0 = blockIdx.y * 32;
  #pragma unroll
  for (int i = 0; i < 4; ++i) {
    int r = r0 + ly + i * 8, c = c0 + lx;
    if (r < R && c < C) tile[ly + i * 8][lx] = src[(size_t)r * C + c];
  }
  __syncthreads();
  #pragma unroll
  for (int i = 0; i < 4; ++i) {
    int c = c0 + ly + i * 8, r = r0 + lx;
    if (r < R && c < C) dst[(size_t)c * R + r] = tile[lx][ly + i * 8];
  }
}

// ---------------- init: sos row, step-0 control, x assembly ----------------
__global__ void kinit(float* ws, float* out, const float* __restrict__ z,
                      const int* __restrict__ templates, const float* __restrict__ temp_outputs,
                      const float* __restrict__ embedding) {
  const int bid = blockIdx.x, t = threadIdx.x;
  if (bid < 1882) { // sos rows: 16*30100 elements
    int e = bid * 256 + t;
    if (e < 16 * 30100) {
      int b = e / 30100, v = e % 30100;
      out[(size_t)b * OUT_BSTRIDE + v] = (v == 1) ? 1.0f : 0.0f;
    }
    return;
  }
  const int b = bid - 1882; // 0..15
  // control of scan step 0 with carry0
  const int tpl0 = templates[b * 50];
  const int ps = 1, eos = 1;
  const int eos_new = (ps == 6) ? eos : ps; // = 1
  const bool flag = (tpl0 != 5) || (ps == 6);
  const int index = flag ? 1 : 0;
  const int clen = flag ? 0 : 1;
  const int seg = templates[b * 50 + index];
  const int sampled2 = flag ? seg : 1;
  const int sampled3 = (sampled2 == 6) ? eos_new : sampled2;
  const int idx_emb = (sampled3 > 30000) ? 3 : (sampled3 > 29999 ? 29999 : sampled3);
  float* xg = ws + WS_XG;
  for (int d = t; d < 512; d += 256) {
    float zv = z[b * 512 + d];
    xg[d * 16 + b] = zv;                 // pre_hidden part
    ws[WS_PREH + b * 512 + d] = zv;
    xg[(512 + d) * 16 + b] = temp_outputs[(size_t)(b * 50 + index) * 512 + d];
    xg[(1024 + d) * 16 + b] = 0.0f;      // sel_read = 0
  }
  for (int d = t; d < 300; d += 256)
    xg[(1536 + d) * 16 + b] = embedding[(size_t)idx_emb * 300 + d];
  if (t == 0) {
    int* ip = (int*)ws;
    ip[WS_INTS + IP_EOS + b] = eos_new;
    ip[WS_INTS + IP_PS + b] = sampled2;
    ip[WS_INTS + IP_SEG + b] = seg;
    ip[WS_INTS + IP_IDX + b] = index;
    ip[WS_INTS + IP_CLEN + b] = clen;
    out[IDX_OFF + b * 50 + 0] = 1.0f;
    out[IDX_OFF + b * 50 + 1] = (float)sampled2;
  }
}

// ---------------- K1: gi/gh partial GEMV (transposed weights) ----------------
__global__ void k1(float* ws) {
  const int bid = blockIdx.x, t = threadIdx.x;
  const int lane = t & 63;
  const int bq = __builtin_amdgcn_readfirstlane(t >> 6);
  const int b0 = bq * 4;
  const float* xg = ws + WS_XG;
  const bool is_gi = bid < 192;
  const int sub = is_gi ? bid : bid - 192;
  const int jc = sub >> 3, ks = sub & 7;
  const int j = jc * 64 + lane;
  const float* W;
  int d0, d1;
  float* pout;
  if (is_gi) {
    W = ws + WS_WT_IH; d0 = ks * 230; d1 = d0 + 230; if (d1 > 1836) d1 = 1836;
    pout = ws + WS_PGI;
  } else {
    W = ws + WS_WT_HH; d0 = ks * 64; d1 = d0 + 64;
    pout = ws + WS_PGH;
  }
  float a0 = 0.f, a1 = 0.f, a2 = 0.f, a3 = 0.f;
  const float* xrow = xg + b0;
  for (int d = d0; d < d1; ++d) {
    float w = W[(size_t)d * 1536 + j];
    float4 xv = *(const float4*)(xrow + d * 16);
    a0 += w * xv.x; a1 += w * xv.y; a2 += w * xv.z; a3 += w * xv.w;
  }
  *(float4*)(pout + ((size_t)ks * 1536 + j) * 16 + b0) = make_float4(a0, a1, a2, a3);
}

// ---------------- K1b: combine + GRU gates -> hidden ----------------
__global__ void k1b(float* ws, const float* __restrict__ bih, const float* __restrict__ bhh) {
  const int bid = blockIdx.x;
  const int b = bid >> 1;
  const int j = (bid & 1) * 256 + threadIdx.x;
  float gir = 0.f, giz = 0.f, gin = 0.f, ghr = 0.f, ghz = 0.f, ghn = 0.f;
  #pragma unroll
  for (int ks = 0; ks < 8; ++ks) {
    const float* pg = ws + WS_PGI + (size_t)ks * 1536 * 16;
    gir += pg[j * 16 + b]; giz += pg[(512 + j) * 16 + b]; gin += pg[(1024 + j) * 16 + b];
    const float* ph = ws + WS_PGH + (size_t)ks * 1536 * 16;
    ghr += ph[j * 16 + b]; ghz += ph[(512 + j) * 16 + b]; ghn += ph[(1024 + j) * 16 + b];
  }
  gir += bih[j]; giz += bih[512 + j]; gin += bih[1024 + j];
  ghr += bhh[j]; ghz += bhh[512 + j]; ghn += bhh[1024 + j];
  float r  = 1.f / (1.f + expf(-(gir + ghr)));
  float zg = 1.f / (1.f + expf(-(giz + ghz)));
  float n  = tanhf(gin + r * ghn);
  float h  = ws[WS_PREH + b * 512 + j];
  float hn = (1.f - zg) * n + zg * h;
  ws[WS_HID + b * 512 + j] = hn;
  ws[WS_X2 + (size_t)(512 + j) * 16 + b] = hn;
}

// ---------------- K2: th/th2 partial GEMV ----------------
__global__ void k2(float* ws) {
  const int bid = blockIdx.x, t = threadIdx.x;
  const int lane = t & 63;
  const int bq = __builtin_amdgcn_readfirstlane(t >> 6);
  const int b0 = bq * 4;
  const bool is_th = bid < 32;
  const int sub = is_th ? bid : bid - 32;
  const int jc = sub >> 2, ks = sub & 3;
  const int j = jc * 64 + lane;
  const float* W = ws + (is_th ? WS_WT_AT : WS_WT_CP);
  float* pout = ws + (is_th ? WS_PTH : WS_PTH2);
  const float* xh = ws + WS_X2 + 512 * 16 + b0; // hidden part
  const int d0 = ks * 128, d1 = d0 + 128;
  float a0 = 0.f, a1 = 0.f, a2 = 0.f, a3 = 0.f;
  for (int d = d0; d < d1; ++d) {
    float w = W[(size_t)d * 512 + j];
    float4 xv = *(const float4*)(xh + d * 16);
    a0 += w * xv.x; a1 += w * xv.y; a2 += w * xv.z; a3 += w * xv.w;
  }
  *(float4*)(pout + ((size_t)ks * 512 + j) * 16 + b0) = make_float4(a0, a1, a2, a3);
}

// ---------------- K2b: attention softmax, context, css, copy prep ----------------
__global__ void k2b(float* ws, const float* __restrict__ attn_b, const float* __restrict__ copy_b,
                    const float* __restrict__ enc, const int* __restrict__ inputs) {
  const int b = blockIdx.x, t = threadIdx.x;
  __shared__ float th_s[512], th2_s[512];
  __shared__ float sc_s[128], css_s[128], e_s[128];
  __shared__ float aw_s[100];
  __shared__ int   tok_s[100];
  __shared__ float gs_s[100];
  __shared__ int   valid_s[100];
  __shared__ float red[256];

  for (int j = t; j < 512; j += 256) {
    float s1 = attn_b[j], s2 = copy_b[j];
    #pragma unroll
    for (int ks = 0; ks < 4; ++ks) {
      s1 += ws[WS_PTH  + ((size_t)ks * 512 + j) * 16 + b];
      s2 += ws[WS_PTH2 + ((size_t)ks * 512 + j) * 16 + b];
    }
    th_s[j] = s1; th2_s[j] = s2;
  }
  if (t < 128) { sc_s[t] = -1e30f; css_s[t] = 0.f; }
  if (t < 100) tok_s[t] = inputs[b * 100 + t];
  __syncthreads();

  const int w = t >> 6, lane = t & 63;
  for (int s = w; s < 100; s += 4) {
    const float* er = enc + (size_t)(b * 100 + s) * 512;
    float p1 = 0.f, p2 = 0.f;
    #pragma unroll
    for (int i = 0; i < 8; ++i) {
      float e = er[lane + 64 * i];
      p1 += e * th_s[lane + 64 * i];
      p2 += e * th2_s[lane + 64 * i];
    }
    for (int off = 32; off > 0; off >>= 1) { p1 += __shfl_down(p1, off); p2 += __shfl_down(p2, off); }
    if (lane == 0) { sc_s[s] = p1; css_s[s] = p2; ws[WS_CSS + b * 100 + s] = p2; }
  }
  __syncthreads();

  // softmax over 100 scores
  if (t < 64) {
    float m = fmaxf(sc_s[t], sc_s[t + 64]);
    for (int off = 32; off > 0; off >>= 1) m = fmaxf(m, __shfl_down(m, off));
    if (t == 0) red[0] = m;
  }
  __syncthreads();
  const float m = red[0];
  if (t < 128) e_s[t] = (t < 100) ? expf(sc_s[t] - m) : 0.f;
  __syncthreads();
  if (t < 64) {
    float ss = e_s[t] + e_s[t + 64];
    for (int off = 32; off > 0; off >>= 1) ss += __shfl_down(ss, off);
    if (t == 0) red[1] = ss;
  }
  __syncthreads();
  const float inv = 1.f / red[1];
  if (t < 100) aw_s[t] = e_s[t] * inv;
  __syncthreads();

  // context -> x2[0:512]
  for (int d = t; d < 512; d += 256) {
    float c = 0.f;
    for (int s = 0; s < 100; ++s) c += aw_s[s] * enc[(size_t)(b * 100 + s) * 512 + d];
    ws[WS_X2 + (size_t)d * 16 + b] = c;
  }

  // copy-score dedupe, safe max M, exp values
  if (t < 100) {
    int tok = tok_s[t]; float gs = 0.f; bool first = true;
    for (int s2 = 0; s2 < 100; ++s2) {
      if (tok_s[s2] == tok) { gs += css_s[s2]; if (s2 < t) first = false; }
    }
    gs_s[t] = gs; valid_s[t] = (first && tok != 0) ? 1 : 0;
  }
  __syncthreads();
  if (t < 64) {
    float v1 = (t < 100 && valid_s[t]) ? gs_s[t] : -1e30f;
    float v2 = ((t + 64) < 100 && valid_s[t + 64]) ? gs_s[t + 64] : -1e30f;
    float m2 = fmaxf(v1, v2);
    for (int off = 32; off > 0; off >>= 1) m2 = fmaxf(m2, __shfl_down(m2, off));
    if (t == 0) red[2] = fmaxf(m2, 0.f);
  }
  __syncthreads();
  const float M = red[2];
  float cv = 0.f;
  if (t < 100) {
    cv = valid_s[t] ? expf(gs_s[t] - M) : 0.f;
    ws[WS_CVAL + b * 100 + t] = cv;
    ((int*)ws)[WS_INTS + IP_CTOK + b * 100 + t] = tok_s[t];
  }
  red[t] = cv;
  __syncthreads();
  for (int off = 128; off > 0; off >>= 1) { if (t < off) red[t] += red[t + off]; __syncthreads(); }
  if (t == 0) { ws[WS_COPYZ + b] = red[0]; ws[WS_MCUR + b] = M; }
}

// ---------------- K3: big projection + exp + Z partials ----------------
__global__ void k3(float* ws, const float* __restrict__ outb, float* out, int step) {
  const int bid = blockIdx.x, t = threadIdx.x;
  const int lane = t & 63;
  const int bq = __builtin_amdgcn_readfirstlane(t >> 6);
  const int b0 = bq * 4;
  const int v = bid * 64 + lane;
  const float* Wt = ws + WS_WT_OUT;
  const float* xrow = ws + WS_X2 + b0;
  float p0 = 0.f, p1 = 0.f, p2 = 0.f, p3 = 0.f;
  if (v < 30000) {
    float a0 = 0.f, a1 = 0.f, a2 = 0.f, a3 = 0.f;
    #pragma unroll 8
    for (int k = 0; k < 1024; ++k) {
      float wv = Wt[(size_t)k * 30000 + v];
      float4 xv = *(const float4*)(xrow + k * 16);
      a0 += wv * xv.x; a1 += wv * xv.y; a2 += wv * xv.z; a3 += wv * xv.w;
    }
    if (v != 0) {
      const float bb = outb[v];
      p0 = expf(a0 + bb - ws[WS_MCUR + b0 + 0]);
      p1 = expf(a1 + bb - ws[WS_MCUR + b0 + 1]);
      p2 = expf(a2 + bb - ws[WS_MCUR + b0 + 2]);
      p3 = expf(a3 + bb - ws[WS_MCUR + b0 + 3]);
    }
  }
  if (v < 30100) {
    const size_t rb = (size_t)(step + 1) * 30100 + v;
    out[(size_t)(b0 + 0) * OUT_BSTRIDE + rb] = p0;
    out[(size_t)(b0 + 1) * OUT_BSTRIDE + rb] = p1;
    out[(size_t)(b0 + 2) * OUT_BSTRIDE + rb] = p2;
    out[(size_t)(b0 + 3) * OUT_BSTRIDE + rb] = p3;
  }
  // wave-level Z partial sums
  float s0 = p0, s1 = p1, s2 = p2, s3 = p3;
  for (int off = 32; off > 0; off >>= 1) {
    s0 += __shfl_down(s0, off); s1 += __shfl_down(s1, off);
    s2 += __shfl_down(s2, off); s3 += __shfl_down(s3, off);
  }
  __shared__ float wp[4][4];
  if (lane == 0) { wp[bq][0] = s0; wp[bq][1] = s1; wp[bq][2] = s2; wp[bq][3] = s3; }
  __syncthreads();
  if (t < 16) ws[WS_ZPART + (size_t)bid * 16 + t] = wp[t >> 2][t & 3];
}

// ---------------- K4b: Z, copy scatter, argmax, sel, next-step control ----------------
__global__ void k4b(float* ws, float* out, const float* __restrict__ enc, const int* __restrict__ inputs,
                    const int* __restrict__ templates, const float* __restrict__ temp_outputs,
                    const float* __restrict__ embedding, int step) {
  const int b = blockIdx.x, t = threadIdx.x;
  int* ip = (int*)ws;
  const size_t row = (size_t)b * OUT_BSTRIDE + (size_t)(step + 1) * 30100;
  __shared__ float red[256];
  __shared__ int redi[256];
  __shared__ float selv_s[100];
  __shared__ float sh_inv;

  // Z total
  float zp = 0.f;
  for (int i = t; i < 471; i += 256) zp += ws[WS_ZPART + (size_t)i * 16 + b];
  red[t] = zp; __syncthreads();
  for (int off = 128; off > 0; off >>= 1) { if (t < off) red[t] += red[t + off]; __syncthreads(); }
  if (t == 0) ws[WS_ZTOT + step * 16 + b] = red[0] + ws[WS_COPYZ + b];
  __syncthreads();

  // scatter copy exps into output row (unique tokens only)
  if (t < 100) {
    float cv = ws[WS_CVAL + b * 100 + t];
    if (cv > 0.f) {
      int tok = ip[WS_INTS + IP_CTOK + b * 100 + t];
      out[row + tok] += cv;
    }
  }
  __syncthreads();
  if (step >= 48) return; // last step: no next-state needed

  // argmax over full row (lowest index on ties)
  float bp = -1.f; int bv = 0;
  for (int v = t; v < 30100; v += 256) {
    float p = out[row + v];
    if (p > bp) { bp = p; bv = v; }
  }
  red[t] = bp; redi[t] = bv; __syncthreads();
  for (int off = 128; off > 0; off >>= 1) {
    if (t < off) {
      float po = red[t + off]; int vo = redi[t + off];
      if (po > red[t] || (po == red[t] && vo < redi[t])) { red[t] = po; redi[t] = vo; }
    }
    __syncthreads();
  }
  const int samp = redi[0];
  __syncthreads();

  // sel = pos*css, L1-normalized
  float sv = 0.f;
  if (t < 100) {
    sv = (inputs[b * 100 + t] == samp) ? ws[WS_CSS + b * 100 + t] : 0.f;
    selv_s[t] = sv;
  }
  red[t] = (t < 100) ? fabsf(sv) : 0.f;
  __syncthreads();
  for (int off = 128; off > 0; off >>= 1) { if (t < off) red[t] += red[t + off]; __syncthreads(); }
  if (t == 0) sh_inv = 1.f / fmaxf(red[0], 1e-12f);
  __syncthreads();
  if (t < 100) selv_s[t] = selv_s[t] * sh_inv;
  __syncthreads();

  // control for next scan step
  const int ps = ip[WS_INTS + IP_PS + b], eos = ip[WS_INTS + IP_EOS + b];
  const int preseg = ip[WS_INTS + IP_SEG + b], index = ip[WS_INTS + IP_IDX + b];
  const int clen = ip[WS_INTS + IP_CLEN + b];
  const int eos_new = (ps == 6) ? eos : ps;
  const bool flag = (preseg != 5) || (ps == 6) || (clen > 20);
  const int index_n = index + (flag ? 1 : 0);
  const int clen_n = clen + (flag ? 0 : 1);
  const int seg = templates[b * 50 + index_n];
  const int sampled2 = flag ? seg : samp;
  const bool keep = (sampled2 == 5) || (sampled2 == 6);
  const int sampled3 = (sampled2 == 6) ? eos_new : sampled2;
  const int idx_emb = (sampled3 > 30000) ? 3 : (sampled3 > 29999 ? 29999 : sampled3);

  float* xg = ws + WS_XG;
  for (int d = t; d < 512; d += 256) {
    float phv = keep ? ws[WS_PREH + b * 512 + d] : ws[WS_HID + b * 512 + d];
    ws[WS_PREH + b * 512 + d] = phv;
    xg[d * 16 + b] = phv;
    xg[(512 + d) * 16 + b] = temp_outputs[(size_t)(b * 50 + index_n) * 512 + d];
    float sr = 0.f;
    for (int s = 0; s < 100; ++s) sr += selv_s[s] * enc[(size_t)(b * 100 + s) * 512 + d];
    xg[(1024 + d) * 16 + b] = sr;
  }
  for (int d = t; d < 300; d += 256)
    xg[(1536 + d) * 16 + b] = embedding[(size_t)idx_emb * 300 + d];
  if (t == 0) {
    ip[WS_INTS + IP_PS + b] = sampled2;
    ip[WS_INTS + IP_EOS + b] = eos_new;
    ip[WS_INTS + IP_SEG + b] = seg;
    ip[WS_INTS + IP_IDX + b] = index_n;
    ip[WS_INTS + IP_CLEN + b] = clen_n;
    out[IDX_OFF + b * 50 + step + 2] = (float)sampled2;
  }
}

// ---------------- final normalize (rows 1..49) ----------------
__global__ void knorm(const float* __restrict__ ws, float* out) {
  const int e = blockIdx.x * 256 + threadIdx.x;
  if (e >= 23598400) return; // 16*49*30100
  const int b = e / 1474900;       // 49*30100
  const int r2 = e - b * 1474900;
  const int r = r2 / 30100;
  const int v = r2 - r * 30100;
  out[(size_t)b * OUT_BSTRIDE + (size_t)(r + 1) * 30100 + v] /= ws[WS_ZTOT + r * 16 + b];
}

extern "C" void kernel_launch(void* const* d_in, const int* in_sizes, int n_in,
                              void* d_out, int out_size, void* d_ws, size_t ws_size,
                              hipStream_t stream) {
  const float* enc       = (const float*)d_in[0];
  const float* temp_out  = (const float*)d_in[1];
  const float* z         = (const float*)d_in[2];
  const float* embedding = (const float*)d_in[3];
  const float* gru_w_ih  = (const float*)d_in[4];
  const float* gru_w_hh  = (const float*)d_in[5];
  const float* gru_b_ih  = (const float*)d_in[6];
  const float* gru_b_hh  = (const float*)d_in[7];
  const float* attn_w    = (const float*)d_in[8];
  const float* attn_b    = (const float*)d_in[9];
  const float* copy_w    = (const float*)d_in[10];
  const float* copy_b    = (const float*)d_in[11];
  const float* out_w     = (const float*)d_in[12];
  const float* out_b     = (const float*)d_in[13];
  const int*   templates = (const int*)d_in[14];
  const int*   inputs    = (const int*)d_in[15];
  float* out = (float*)d_out;
  float* ws  = (float*)d_ws;

  // transposes into workspace (every call; ws is re-poisoned by the harness)
  ktrans<<<dim3(938, 32), 256, 0, stream>>>(out_w, ws + WS_WT_OUT, 30000, 1024);
  ktrans<<<dim3(48, 58), 256, 0, stream>>>(gru_w_ih, ws + WS_WT_IH, 1536, 1836);
  ktrans<<<dim3(48, 16), 256, 0, stream>>>(gru_w_hh, ws + WS_WT_HH, 1536, 512);
  ktrans<<<dim3(16, 16), 256, 0, stream>>>(attn_w, ws + WS_WT_AT, 512, 512);
  ktrans<<<dim3(16, 16), 256, 0, stream>>>(copy_w, ws + WS_WT_CP, 512, 512);

  kinit<<<1898, 256, 0, stream>>>(ws, out, z, templates, temp_out, embedding);

  for (int step = 0; step < 49; ++step) {
    k1<<<384, 256, 0, stream>>>(ws);
    k1b<<<32, 256, 0, stream>>>(ws, gru_b_ih, gru_b_hh);
    k2<<<64, 256, 0, stream>>>(ws);
    k2b<<<16, 256, 0, stream>>>(ws, attn_b, copy_b, enc, inputs);
    k3<<<471, 256, 0, stream>>>(ws, out_b, out, step);
    k4b<<<16, 256, 0, stream>>>(ws, out, enc, inputs, templates, temp_out, embedding, step);
  }

  knorm<<<92182, 256, 0, stream>>>(ws, out);
}

// Round 2
// 9790.301 us; speedup vs baseline: 1.1868x; 1.1868x over previous
//
#include <hip/hip_runtime.h>
#include <math.h>

// B=16, S=100, V=30000, H=512, E=300, T=50, MAXLEN=50, D=3H+E=1836
#define NEGV (-1000000.0f)

// ---- workspace layout (float element offsets) ----
constexpr size_t WS_WT_OUT = 0;           // bf16 [1024][30000] ushort = 15,360,000 floats
constexpr size_t WS_WT_IH  = 15360000;    // [1836][1536] f32
constexpr size_t WS_WT_HH  = 18180096;    // [512][1536]
constexpr size_t WS_WT_AT  = 18966528;    // [512][512]
constexpr size_t WS_WT_CP  = 19228672;    // [512][512]
constexpr size_t WS_XG     = 19490816;    // [1836][16]
constexpr size_t WS_X2     = 19520192;    // [1024][16]
constexpr size_t WS_PGI    = 19536576;    // [8][1536][16]
constexpr size_t WS_PGH    = 19733184;    // [8][1536][16]
constexpr size_t WS_PTH    = 19929792;    // [4][512][16]
constexpr size_t WS_PTH2   = 19962560;    // [4][512][16]
constexpr size_t WS_HID    = 19995328;    // [16][512]
constexpr size_t WS_PREH   = 20003520;    // [16][512]
constexpr size_t WS_CSS    = 20011712;    // [16][100]
constexpr size_t WS_CVAL   = 20013312;    // [16][100]
constexpr size_t WS_COPYZ  = 20014912;    // [16]
constexpr size_t WS_MCUR   = 20014928;    // [16]
constexpr size_t WS_ZPART  = 20014944;    // [471][16]
constexpr size_t WS_ZTOT   = 20022480;    // [49][16]
constexpr size_t WS_AMV    = 20023264;    // [471][16] argmax partial values
constexpr size_t WS_INTS   = 20030800;    // int region base (as float idx)
// int region sub-offsets (ints)
constexpr size_t IP_CTOK = 0;     // [16][100]
constexpr size_t IP_EOS  = 1600;  // [16]
constexpr size_t IP_PS   = 1616;
constexpr size_t IP_SEG  = 1632;
constexpr size_t IP_IDX  = 1648;
constexpr size_t IP_CLEN = 1664;
constexpr size_t IP_AMI  = 1680;  // [471][16] argmax partial indices
// total ~20,040,016 floats = 80.2 MB

constexpr size_t OUT_BSTRIDE = 1505000; // 50*30100
constexpr size_t IDX_OFF = 24080000;    // 16*50*30100

__device__ inline unsigned short f2bf(float x) {
  unsigned u = __float_as_uint(x);
  unsigned r = (u + 0x7fffu + ((u >> 16) & 1u)) >> 16;
  return (unsigned short)r;
}

// ---------------- transpose f32: dst[C][R] = src[R][C] ----------------
__global__ void ktrans(const float* __restrict__ src, float* __restrict__ dst, int R, int C) {
  __shared__ float tile[32][33];
  const int t = threadIdx.x;
  const int lx = t & 31, ly = t >> 5;
  const int r0 = blockIdx.x * 32, c0 = blockIdx.y * 32;
  #pragma unroll
  for (int i = 0; i < 4; ++i) {
    int r = r0 + ly + i * 8, c = c0 + lx;
    if (r < R && c < C) tile[ly + i * 8][lx] = src[(size_t)r * C + c];
  }
  __syncthreads();
  #pragma unroll
  for (int i = 0; i < 4; ++i) {
    int c = c0 + ly + i * 8, r = r0 + lx;
    if (r < R && c < C) dst[(size_t)c * R + r] = tile[lx][ly + i * 8];
  }
}

// ---------------- transpose to bf16: dst[C][R] = bf16(src[R][C]) ----------------
__global__ void ktransb(const float* __restrict__ src, unsigned short* __restrict__ dst, int R, int C) {
  __shared__ float tile[32][33];
  const int t = threadIdx.x;
  const int lx = t & 31, ly = t >> 5;
  const int r0 = blockIdx.x * 32, c0 = blockIdx.y * 32;
  #pragma unroll
  for (int i = 0; i < 4; ++i) {
    int r = r0 + ly + i * 8, c = c0 + lx;
    if (r < R && c < C) tile[ly + i * 8][lx] = src[(size_t)r * C + c];
  }
  __syncthreads();
  #pragma unroll
  for (int i = 0; i < 4; ++i) {
    int c = c0 + ly + i * 8, r = r0 + lx;
    if (r < R && c < C) dst[(size_t)c * R + r] = f2bf(tile[lx][ly + i * 8]);
  }
}

// ---------------- init: sos rows, step-0 control, x assembly ----------------
__global__ void kinit(float* ws, float* out, const float* __restrict__ z,
                      const int* __restrict__ templates, const float* __restrict__ temp_outputs,
                      const float* __restrict__ embedding) {
  const int bid = blockIdx.x, t = threadIdx.x;
  if (bid < 1882) {
    int e = bid * 256 + t;
    if (e < 16 * 30100) {
      int b = e / 30100, v = e % 30100;
      out[(size_t)b * OUT_BSTRIDE + v] = (v == 1) ? 1.0f : 0.0f;
    }
    return;
  }
  const int b = bid - 1882;
  const int tpl0 = templates[b * 50];
  const int ps = 1, eos = 1;
  const int eos_new = (ps == 6) ? eos : ps;
  const bool flag = (tpl0 != 5) || (ps == 6);
  const int index = flag ? 1 : 0;
  const int clen = flag ? 0 : 1;
  const int seg = templates[b * 50 + index];
  const int sampled2 = flag ? seg : 1;
  const int sampled3 = (sampled2 == 6) ? eos_new : sampled2;
  const int idx_emb = (sampled3 > 30000) ? 3 : (sampled3 > 29999 ? 29999 : sampled3);
  float* xg = ws + WS_XG;
  for (int d = t; d < 512; d += 256) {
    float zv = z[b * 512 + d];
    xg[d * 16 + b] = zv;
    ws[WS_PREH + b * 512 + d] = zv;
    xg[(512 + d) * 16 + b] = temp_outputs[(size_t)(b * 50 + index) * 512 + d];
    xg[(1024 + d) * 16 + b] = 0.0f;
  }
  for (int d = t; d < 300; d += 256)
    xg[(1536 + d) * 16 + b] = embedding[(size_t)idx_emb * 300 + d];
  if (t == 0) {
    int* ip = (int*)ws;
    ip[WS_INTS + IP_EOS + b] = eos_new;
    ip[WS_INTS + IP_PS + b] = sampled2;
    ip[WS_INTS + IP_SEG + b] = seg;
    ip[WS_INTS + IP_IDX + b] = index;
    ip[WS_INTS + IP_CLEN + b] = clen;
    out[IDX_OFF + b * 50 + 0] = 1.0f;
    out[IDX_OFF + b * 50 + 1] = (float)sampled2;
  }
}

// ---------------- K1: gi/gh partial GEMV ----------------
__global__ __launch_bounds__(256) void k1(float* ws) {
  const int bid = blockIdx.x, t = threadIdx.x;
  const int lane = t & 63;
  const int bq = __builtin_amdgcn_readfirstlane(t >> 6);
  const int b0 = bq * 4;
  const float* xg = ws + WS_XG;
  const bool is_gi = bid < 192;
  const int sub = is_gi ? bid : bid - 192;
  const int jc = sub >> 3, ks = sub & 7;
  const int j = jc * 64 + lane;
  const float* W;
  int d0, d1;
  float* pout;
  if (is_gi) {
    W = ws + WS_WT_IH; d0 = ks * 230; d1 = d0 + 230; if (d1 > 1836) d1 = 1836;
    pout = ws + WS_PGI;
  } else {
    W = ws + WS_WT_HH; d0 = ks * 64; d1 = d0 + 64;
    pout = ws + WS_PGH;
  }
  float a0 = 0.f, a1 = 0.f, a2 = 0.f, a3 = 0.f;
  const float* xrow = xg + b0;
  for (int d = d0; d < d1; ++d) {
    float w = W[(size_t)d * 1536 + j];
    float4 xv = *(const float4*)(xrow + d * 16);
    a0 += w * xv.x; a1 += w * xv.y; a2 += w * xv.z; a3 += w * xv.w;
  }
  *(float4*)(pout + ((size_t)ks * 1536 + j) * 16 + b0) = make_float4(a0, a1, a2, a3);
}

// ---------------- K1b: combine + GRU gates -> hidden ----------------
__global__ __launch_bounds__(256) void k1b(float* ws, const float* __restrict__ bih, const float* __restrict__ bhh) {
  const int bid = blockIdx.x;
  const int b = bid >> 1;
  const int j = (bid & 1) * 256 + threadIdx.x;
  float gir = 0.f, giz = 0.f, gin = 0.f, ghr = 0.f, ghz = 0.f, ghn = 0.f;
  #pragma unroll
  for (int ks = 0; ks < 8; ++ks) {
    const float* pg = ws + WS_PGI + (size_t)ks * 1536 * 16;
    gir += pg[j * 16 + b]; giz += pg[(512 + j) * 16 + b]; gin += pg[(1024 + j) * 16 + b];
    const float* ph = ws + WS_PGH + (size_t)ks * 1536 * 16;
    ghr += ph[j * 16 + b]; ghz += ph[(512 + j) * 16 + b]; ghn += ph[(1024 + j) * 16 + b];
  }
  gir += bih[j]; giz += bih[512 + j]; gin += bih[1024 + j];
  ghr += bhh[j]; ghz += bhh[512 + j]; ghn += bhh[1024 + j];
  float r  = 1.f / (1.f + expf(-(gir + ghr)));
  float zg = 1.f / (1.f + expf(-(giz + ghz)));
  float n  = tanhf(gin + r * ghn);
  float h  = ws[WS_PREH + b * 512 + j];
  float hn = (1.f - zg) * n + zg * h;
  ws[WS_HID + b * 512 + j] = hn;
  ws[WS_X2 + (size_t)(512 + j) * 16 + b] = hn;
}

// ---------------- K2: th/th2 partial GEMV ----------------
__global__ __launch_bounds__(256) void k2(float* ws) {
  const int bid = blockIdx.x, t = threadIdx.x;
  const int lane = t & 63;
  const int bq = __builtin_amdgcn_readfirstlane(t >> 6);
  const int b0 = bq * 4;
  const bool is_th = bid < 32;
  const int sub = is_th ? bid : bid - 32;
  const int jc = sub >> 2, ks = sub & 3;
  const int j = jc * 64 + lane;
  const float* W = ws + (is_th ? WS_WT_AT : WS_WT_CP);
  float* pout = ws + (is_th ? WS_PTH : WS_PTH2);
  const float* xh = ws + WS_X2 + 512 * 16 + b0;
  const int d0 = ks * 128, d1 = d0 + 128;
  float a0 = 0.f, a1 = 0.f, a2 = 0.f, a3 = 0.f;
  for (int d = d0; d < d1; ++d) {
    float w = W[(size_t)d * 512 + j];
    float4 xv = *(const float4*)(xh + d * 16);
    a0 += w * xv.x; a1 += w * xv.y; a2 += w * xv.z; a3 += w * xv.w;
  }
  *(float4*)(pout + ((size_t)ks * 512 + j) * 16 + b0) = make_float4(a0, a1, a2, a3);
}

// ---------------- K2b: attention softmax, context, css, copy prep ----------------
__global__ __launch_bounds__(256) void k2b(float* ws, const float* __restrict__ attn_b, const float* __restrict__ copy_b,
                    const float* __restrict__ enc, const int* __restrict__ inputs) {
  const int b = blockIdx.x, t = threadIdx.x;
  __shared__ float th_s[512], th2_s[512];
  __shared__ float sc_s[128], css_s[128], e_s[128];
  __shared__ float aw_s[100];
  __shared__ int   tok_s[100];
  __shared__ float gs_s[100];
  __shared__ int   valid_s[100];
  __shared__ float red[256];

  for (int j = t; j < 512; j += 256) {
    float s1 = attn_b[j], s2 = copy_b[j];
    #pragma unroll
    for (int ks = 0; ks < 4; ++ks) {
      s1 += ws[WS_PTH  + ((size_t)ks * 512 + j) * 16 + b];
      s2 += ws[WS_PTH2 + ((size_t)ks * 512 + j) * 16 + b];
    }
    th_s[j] = s1; th2_s[j] = s2;
  }
  if (t < 128) { sc_s[t] = -1e30f; css_s[t] = 0.f; }
  if (t < 100) tok_s[t] = inputs[b * 100 + t];
  __syncthreads();

  const int w = t >> 6, lane = t & 63;
  for (int s = w; s < 100; s += 4) {
    const float* er = enc + (size_t)(b * 100 + s) * 512;
    float p1 = 0.f, p2 = 0.f;
    #pragma unroll
    for (int i = 0; i < 8; ++i) {
      float e = er[lane + 64 * i];
      p1 += e * th_s[lane + 64 * i];
      p2 += e * th2_s[lane + 64 * i];
    }
    for (int off = 32; off > 0; off >>= 1) { p1 += __shfl_down(p1, off); p2 += __shfl_down(p2, off); }
    if (lane == 0) { sc_s[s] = p1; css_s[s] = p2; ws[WS_CSS + b * 100 + s] = p2; }
  }
  __syncthreads();

  if (t < 64) {
    float m = fmaxf(sc_s[t], sc_s[t + 64]);
    for (int off = 32; off > 0; off >>= 1) m = fmaxf(m, __shfl_down(m, off));
    if (t == 0) red[0] = m;
  }
  __syncthreads();
  const float m = red[0];
  if (t < 128) e_s[t] = (t < 100) ? expf(sc_s[t] - m) : 0.f;
  __syncthreads();
  if (t < 64) {
    float ss = e_s[t] + e_s[t + 64];
    for (int off = 32; off > 0; off >>= 1) ss += __shfl_down(ss, off);
    if (t == 0) red[1] = ss;
  }
  __syncthreads();
  const float inv = 1.f / red[1];
  if (t < 100) aw_s[t] = e_s[t] * inv;
  __syncthreads();

  for (int d = t; d < 512; d += 256) {
    float c = 0.f;
    for (int s = 0; s < 100; ++s) c += aw_s[s] * enc[(size_t)(b * 100 + s) * 512 + d];
    ws[WS_X2 + (size_t)d * 16 + b] = c;
  }

  if (t < 100) {
    int tok = tok_s[t]; float gs = 0.f; bool first = true;
    for (int s2 = 0; s2 < 100; ++s2) {
      if (tok_s[s2] == tok) { gs += css_s[s2]; if (s2 < t) first = false; }
    }
    gs_s[t] = gs; valid_s[t] = (first && tok != 0) ? 1 : 0;
  }
  __syncthreads();
  if (t < 64) {
    float v1 = (t < 100 && valid_s[t]) ? gs_s[t] : -1e30f;
    float v2 = ((t + 64) < 100 && valid_s[t + 64]) ? gs_s[t + 64] : -1e30f;
    float m2 = fmaxf(v1, v2);
    for (int off = 32; off > 0; off >>= 1) m2 = fmaxf(m2, __shfl_down(m2, off));
    if (t == 0) red[2] = fmaxf(m2, 0.f);
  }
  __syncthreads();
  const float M = red[2];
  float cv = 0.f;
  if (t < 100) {
    cv = valid_s[t] ? expf(gs_s[t] - M) : 0.f;
    ws[WS_CVAL + b * 100 + t] = cv;
    ((int*)ws)[WS_INTS + IP_CTOK + b * 100 + t] = tok_s[t];
  }
  red[t] = cv;
  __syncthreads();
  for (int off = 128; off > 0; off >>= 1) { if (t < off) red[t] += red[t + off]; __syncthreads(); }
  if (t == 0) { ws[WS_COPYZ + b] = red[0]; ws[WS_MCUR + b] = M; }
}

// ---------------- K3: big projection (bf16 weights) + exp + Z/argmax partials ----------------
__global__ __launch_bounds__(256) void k3(float* ws, const float* __restrict__ outb, float* out, int step) {
  const int bid = blockIdx.x, t = threadIdx.x;
  const int lane = t & 63;
  const int bq = __builtin_amdgcn_readfirstlane(t >> 6);
  const int b0 = bq * 4;
  const int v = bid * 64 + lane;
  const unsigned short* Wt = (const unsigned short*)(ws + WS_WT_OUT);
  const float* xrow = ws + WS_X2 + b0;
  float p0 = 0.f, p1 = 0.f, p2 = 0.f, p3 = 0.f;
  if (v < 30000) {
    float a0 = 0.f, a1 = 0.f, a2 = 0.f, a3 = 0.f;
    #pragma unroll 16
    for (int k = 0; k < 1024; ++k) {
      unsigned short wu = Wt[(size_t)k * 30000 + v];
      float wv = __uint_as_float(((unsigned)wu) << 16);
      float4 xv = *(const float4*)(xrow + k * 16);
      a0 += wv * xv.x; a1 += wv * xv.y; a2 += wv * xv.z; a3 += wv * xv.w;
    }
    if (v != 0) {
      const float bb = outb[v];
      p0 = expf(a0 + bb - ws[WS_MCUR + b0 + 0]);
      p1 = expf(a1 + bb - ws[WS_MCUR + b0 + 1]);
      p2 = expf(a2 + bb - ws[WS_MCUR + b0 + 2]);
      p3 = expf(a3 + bb - ws[WS_MCUR + b0 + 3]);
    }
  }
  if (v < 30100) {
    const size_t rb = (size_t)(step + 1) * 30100 + v;
    out[(size_t)(b0 + 0) * OUT_BSTRIDE + rb] = p0;
    out[(size_t)(b0 + 1) * OUT_BSTRIDE + rb] = p1;
    out[(size_t)(b0 + 2) * OUT_BSTRIDE + rb] = p2;
    out[(size_t)(b0 + 3) * OUT_BSTRIDE + rb] = p3;
  }
  // Z partials
  float s0 = p0, s1 = p1, s2 = p2, s3 = p3;
  for (int off = 32; off > 0; off >>= 1) {
    s0 += __shfl_down(s0, off); s1 += __shfl_down(s1, off);
    s2 += __shfl_down(s2, off); s3 += __shfl_down(s3, off);
  }
  // argmax partials (per wave, per b) with lowest-index tie-break
  float m0 = p0, m1 = p1, m2 = p2, m3 = p3;
  int i0 = v, i1 = v, i2 = v, i3 = v;
  for (int off = 32; off > 0; off >>= 1) {
    float q; int qi;
    q = __shfl_down(m0, off); qi = __shfl_down(i0, off); if (q > m0 || (q == m0 && qi < i0)) { m0 = q; i0 = qi; }
    q = __shfl_down(m1, off); qi = __shfl_down(i1, off); if (q > m1 || (q == m1 && qi < i1)) { m1 = q; i1 = qi; }
    q = __shfl_down(m2, off); qi = __shfl_down(i2, off); if (q > m2 || (q == m2 && qi < i2)) { m2 = q; i2 = qi; }
    q = __shfl_down(m3, off); qi = __shfl_down(i3, off); if (q > m3 || (q == m3 && qi < i3)) { m3 = q; i3 = qi; }
  }
  __shared__ float wp[4][4];
  if (lane == 0) {
    wp[bq][0] = s0; wp[bq][1] = s1; wp[bq][2] = s2; wp[bq][3] = s3;
    float* amv = ws + WS_AMV + (size_t)bid * 16 + b0;
    int* ami = ((int*)ws) + WS_INTS + IP_AMI + (size_t)bid * 16 + b0;
    amv[0] = m0; amv[1] = m1; amv[2] = m2; amv[3] = m3;
    ami[0] = i0; ami[1] = i1; ami[2] = i2; ami[3] = i3;
  }
  __syncthreads();
  if (t < 16) ws[WS_ZPART + (size_t)bid * 16 + t] = wp[t >> 2][t & 3];
}

// ---------------- K4b: Z, scatter, argmax combine, sel, next-step control ----------------
__global__ __launch_bounds__(256) void k4b(float* ws, float* out, const float* __restrict__ enc, const int* __restrict__ inputs,
                    const int* __restrict__ templates, const float* __restrict__ temp_outputs,
                    const float* __restrict__ embedding, int step) {
  const int b = blockIdx.x, t = threadIdx.x;
  int* ip = (int*)ws;
  const size_t row = (size_t)b * OUT_BSTRIDE + (size_t)(step + 1) * 30100;
  __shared__ float red[256];
  __shared__ int redi[256];
  __shared__ float selv_s[100];
  __shared__ float sh_inv;
  __shared__ float gbv_s; __shared__ int gbi_s;

  // Z total + gen argmax partial reduce in one pass over 471 partials
  float zp = 0.f;
  float bp = -1.f; int bv = 0x7fffffff;
  for (int i = t; i < 471; i += 256) {
    zp += ws[WS_ZPART + (size_t)i * 16 + b];
    float av = ws[WS_AMV + (size_t)i * 16 + b];
    int ai = ip[WS_INTS + IP_AMI + (size_t)i * 16 + b];
    if (av > bp || (av == bp && ai < bv)) { bp = av; bv = ai; }
  }
  red[t] = zp; __syncthreads();
  for (int off = 128; off > 0; off >>= 1) { if (t < off) red[t] += red[t + off]; __syncthreads(); }
  if (t == 0) ws[WS_ZTOT + step * 16 + b] = red[0] + ws[WS_COPYZ + b];
  __syncthreads();
  red[t] = bp; redi[t] = bv; __syncthreads();
  for (int off = 128; off > 0; off >>= 1) {
    if (t < off) {
      float po = red[t + off]; int vo = redi[t + off];
      if (po > red[t] || (po == red[t] && vo < redi[t])) { red[t] = po; redi[t] = vo; }
    }
    __syncthreads();
  }
  if (t == 0) { gbv_s = red[0]; gbi_s = redi[0]; }
  __syncthreads();

  // scatter copy exps (unique tokens)
  float cv = 0.f; int tok = 0;
  if (t < 100) {
    cv = ws[WS_CVAL + b * 100 + t];
    tok = ip[WS_INTS + IP_CTOK + b * 100 + t];
    if (cv > 0.f) out[row + tok] += cv;
  }
  __syncthreads();
  if (step >= 48) return;

  // scatter-candidate max (post-scatter values at scattered tokens)
  float sv_ = -1.f; int si_ = 0x7fffffff;
  if (t < 100 && cv > 0.f) { sv_ = out[row + tok]; si_ = tok; }
  red[t] = sv_; redi[t] = si_; __syncthreads();
  for (int off = 128; off > 0; off >>= 1) {
    if (t < off) {
      float po = red[t + off]; int vo = redi[t + off];
      if (po > red[t] || (po == red[t] && vo < redi[t])) { red[t] = po; redi[t] = vo; }
    }
    __syncthreads();
  }
  int samp;
  {
    float sbv = red[0]; int sbi = redi[0];
    float gv = gbv_s; int gi = gbi_s;
    samp = (sbv > gv || (sbv == gv && sbi < gi)) ? sbi : gi;
  }
  __syncthreads();

  // sel = pos*css, L1-normalized
  float sv = 0.f;
  if (t < 100) {
    sv = (inputs[b * 100 + t] == samp) ? ws[WS_CSS + b * 100 + t] : 0.f;
    selv_s[t] = sv;
  }
  red[t] = (t < 100) ? fabsf(sv) : 0.f;
  __syncthreads();
  for (int off = 128; off > 0; off >>= 1) { if (t < off) red[t] += red[t + off]; __syncthreads(); }
  if (t == 0) sh_inv = 1.f / fmaxf(red[0], 1e-12f);
  __syncthreads();
  if (t < 100) selv_s[t] = selv_s[t] * sh_inv;
  __syncthreads();

  // next-step control
  const int ps = ip[WS_INTS + IP_PS + b], eos = ip[WS_INTS + IP_EOS + b];
  const int preseg = ip[WS_INTS + IP_SEG + b], index = ip[WS_INTS + IP_IDX + b];
  const int clen = ip[WS_INTS + IP_CLEN + b];
  const int eos_new = (ps == 6) ? eos : ps;
  const bool flag = (preseg != 5) || (ps == 6) || (clen > 20);
  const int index_n = index + (flag ? 1 : 0);
  const int clen_n = clen + (flag ? 0 : 1);
  const int seg = templates[b * 50 + index_n];
  const int sampled2 = flag ? seg : samp;
  const bool keep = (sampled2 == 5) || (sampled2 == 6);
  const int sampled3 = (sampled2 == 6) ? eos_new : sampled2;
  const int idx_emb = (sampled3 > 30000) ? 3 : (sampled3 > 29999 ? 29999 : sampled3);

  float* xg = ws + WS_XG;
  for (int d = t; d < 512; d += 256) {
    float phv = keep ? ws[WS_PREH + b * 512 + d] : ws[WS_HID + b * 512 + d];
    ws[WS_PREH + b * 512 + d] = phv;
    xg[d * 16 + b] = phv;
    xg[(512 + d) * 16 + b] = temp_outputs[(size_t)(b * 50 + index_n) * 512 + d];
    float sr = 0.f;
    for (int s = 0; s < 100; ++s) sr += selv_s[s] * enc[(size_t)(b * 100 + s) * 512 + d];
    xg[(1024 + d) * 16 + b] = sr;
  }
  for (int d = t; d < 300; d += 256)
    xg[(1536 + d) * 16 + b] = embedding[(size_t)idx_emb * 300 + d];
  if (t == 0) {
    ip[WS_INTS + IP_PS + b] = sampled2;
    ip[WS_INTS + IP_EOS + b] = eos_new;
    ip[WS_INTS + IP_SEG + b] = seg;
    ip[WS_INTS + IP_IDX + b] = index_n;
    ip[WS_INTS + IP_CLEN + b] = clen_n;
    out[IDX_OFF + b * 50 + step + 2] = (float)sampled2;
  }
}

// ---------------- final normalize (rows 1..49) ----------------
__global__ void knorm(const float* __restrict__ ws, float* out) {
  const int e = blockIdx.x * 256 + threadIdx.x;
  if (e >= 23598400) return;
  const int b = e / 1474900;
  const int r2 = e - b * 1474900;
  const int r = r2 / 30100;
  const int v = r2 - r * 30100;
  out[(size_t)b * OUT_BSTRIDE + (size_t)(r + 1) * 30100 + v] /= ws[WS_ZTOT + r * 16 + b];
}

extern "C" void kernel_launch(void* const* d_in, const int* in_sizes, int n_in,
                              void* d_out, int out_size, void* d_ws, size_t ws_size,
                              hipStream_t stream) {
  const float* enc       = (const float*)d_in[0];
  const float* temp_out  = (const float*)d_in[1];
  const float* z         = (const float*)d_in[2];
  const float* embedding = (const float*)d_in[3];
  const float* gru_w_ih  = (const float*)d_in[4];
  const float* gru_w_hh  = (const float*)d_in[5];
  const float* gru_b_ih  = (const float*)d_in[6];
  const float* gru_b_hh  = (const float*)d_in[7];
  const float* attn_w    = (const float*)d_in[8];
  const float* attn_b    = (const float*)d_in[9];
  const float* copy_w    = (const float*)d_in[10];
  const float* copy_b    = (const float*)d_in[11];
  const float* out_w     = (const float*)d_in[12];
  const float* out_b     = (const float*)d_in[13];
  const int*   templates = (const int*)d_in[14];
  const int*   inputs    = (const int*)d_in[15];
  float* out = (float*)d_out;
  float* ws  = (float*)d_ws;

  ktransb<<<dim3(938, 32), 256, 0, stream>>>(out_w, (unsigned short*)(ws + WS_WT_OUT), 30000, 1024);
  ktrans<<<dim3(48, 58), 256, 0, stream>>>(gru_w_ih, ws + WS_WT_IH, 1536, 1836);
  ktrans<<<dim3(48, 16), 256, 0, stream>>>(gru_w_hh, ws + WS_WT_HH, 1536, 512);
  ktrans<<<dim3(16, 16), 256, 0, stream>>>(attn_w, ws + WS_WT_AT, 512, 512);
  ktrans<<<dim3(16, 16), 256, 0, stream>>>(copy_w, ws + WS_WT_CP, 512, 512);

  kinit<<<1898, 256, 0, stream>>>(ws, out, z, templates, temp_out, embedding);

  for (int step = 0; step < 49; ++step) {
    k1<<<384, 256, 0, stream>>>(ws);
    k1b<<<32, 256, 0, stream>>>(ws, gru_b_ih, gru_b_hh);
    k2<<<64, 256, 0, stream>>>(ws);
    k2b<<<16, 256, 0, stream>>>(ws, attn_b, copy_b, enc, inputs);
    k3<<<471, 256, 0, stream>>>(ws, out_b, out, step);
    k4b<<<16, 256, 0, stream>>>(ws, out, enc, inputs, templates, temp_out, embedding, step);
  }

  knorm<<<92182, 256, 0, stream>>>(ws, out);
}